// Round 1
// baseline (13602.911 us; speedup 1.0000x reference)
//
#include <hip/hip_runtime.h>
#include <math.h>

// ReservoirLayer: B=8, T=4096, R=1024, F=64, I=32
#define TT 4096
#define RR 1024
#define FF 64
#define II 32
#define GROUPS 8                 // one group per batch element
#define BPG 32                   // blocks per group
#define THREADS 256
#define KV4 32                   // float4 of W_hh per thread
#define ALPHA 0.9f
#define TCH 32                   // timesteps per prologue block

typedef unsigned long long u64;
typedef unsigned int u32;
typedef u32 u32x4 __attribute__((ext_vector_type(4)));

#define SLOT_U32 (GROUPS * RR)           // 8192 u32 per parity slot (32 KB)
#define PAD(i) ((i) + (((i) >> 7) << 2)) // +4 floats per 128-float chunk

__device__ __forceinline__ void st_rlx32(u32* p, u32 v) {
    __hip_atomic_store(p, v, __ATOMIC_RELAXED, __HIP_MEMORY_SCOPE_AGENT);
}

// L2-scope (SE-scope, sc0) 16B load: bypasses L1, hits the XCD-local L2.
// The sc1 publish stores write THROUGH that L2, so same-XCD readers see
// fresh data here at ~250cy instead of polling the MALL at ~700cy+.
__device__ __forceinline__ u32x4 ld_l2(const u32x4* p) {
    u32x4 v;
    asm volatile("global_load_dwordx4 %0, %1, off sc0\n\t"
                 "s_waitcnt vmcnt(0)"
                 : "=v"(v) : "v"(p) : "memory");
    return v;
}

// Poll 4 tagged floats. Fast path: sc0 polls (local L2). Robustness: if the
// reader is NOT on the writer's XCD, its L2 can hold a stale clean line
// forever; every 12 stale spins we issue one agent-scope (sc1) load that
// reads the MALL — where the write-through publishes always land — so a
// wrong placement degrades to ~old-kernel speed instead of hanging.
__device__ __forceinline__ u32x4 poll4(const u32x4* p, u32 wtag) {
    u32x4 v = ld_l2(p);
    int spins = 0;
    while ((((v[0] ^ wtag) | (v[1] ^ wtag) | (v[2] ^ wtag) | (v[3] ^ wtag)) & 1u) != 0u) {
        if (++spins >= 12) {
            spins = 0;
            u64 a0 = __hip_atomic_load((const u64*)p,     __ATOMIC_RELAXED, __HIP_MEMORY_SCOPE_AGENT);
            u64 a1 = __hip_atomic_load((const u64*)p + 1, __ATOMIC_RELAXED, __HIP_MEMORY_SCOPE_AGENT);
            v[0] = (u32)a0; v[1] = (u32)(a0 >> 32);
            v[2] = (u32)a1; v[3] = (u32)(a1 >> 32);
        } else {
            v = ld_l2(p);
        }
    }
    return v;
}

// tanh via v_exp_f32: (e^{2|x|}-1)/(e^{2|x|}+1), |x| clamped at 10
// (tanh(10)=1-8e-9 == 1.0f). Error ~2^-21/step, far below the already
// tolerated tag-LSB clobber. ~10 insts vs ocml tanhf's long sequence.
__device__ __forceinline__ float fast_tanh(float x) {
    float ax = fabsf(x);
    float e  = __expf(2.0f * fminf(ax, 10.0f));
    float r  = (e - 1.0f) * __builtin_amdgcn_rcpf(e + 1.0f);
    return x < 0.0f ? -r : r;
}

// ---------------- Prologue: drive[b,t,r] = fb·W_fb^T + dr·W_in^T -> out ----
// out row t is consumed (as drive) at step t of the recurrence and only
// overwritten (with h_t) at step t+1 — safe in-place dataflow. Bias is
// added in the main kernel (brow), matching the reference's u_t + b.
__global__ __launch_bounds__(256, 1)
void drive_pre(const float* __restrict__ feedback,
               const float* __restrict__ driving,
               const float* __restrict__ W_fb,
               const float* __restrict__ W_in,
               float* __restrict__ out)
{
    const int tid = threadIdx.x;
    const int b   = blockIdx.x >> 7;            // 128 chunks per batch
    const int t0  = (blockIdx.x & 127) * TCH;

    __shared__ float xch[TCH][96];              // [t][ fb(64) | dr(32) ]

    const float4* fb4 = (const float4*)(feedback + ((size_t)b * TT + t0) * FF);
    #pragma unroll
    for (int q = 0; q < 2; q++) {
        int i = tid + 256 * q;                  // 0..511 : 32t x 16 float4
        float4 v = fb4[i];
        *(float4*)&xch[i >> 4][(i & 15) << 2] = v;
    }
    {
        const float4* dr4 = (const float4*)(driving + ((size_t)b * TT + t0) * II);
        float4 v = dr4[tid];                    // 0..255 : 32t x 8 float4
        *(float4*)&xch[tid >> 3][64 + ((tid & 7) << 2)] = v;
    }
    __syncthreads();

    #pragma unroll 1
    for (int p = 0; p < 4; p++) {
        const int r = p * 256 + tid;
        float4 w[24];
        const float4* wf4 = (const float4*)(W_fb + (size_t)r * FF);
        #pragma unroll
        for (int q = 0; q < 16; q++) w[q] = wf4[q];
        const float4* wi4 = (const float4*)(W_in + (size_t)r * II);
        #pragma unroll
        for (int q = 0; q < 8; q++) w[16 + q] = wi4[q];

        for (int t = 0; t < TCH; t++) {
            float s = 0.0f;
            #pragma unroll
            for (int q = 0; q < 24; q++) {
                float4 x = *(const float4*)&xch[t][q << 2]; // broadcast read
                s = fmaf(w[q].x, x.x, s);
                s = fmaf(w[q].y, x.y, s);
                s = fmaf(w[q].z, x.z, s);
                s = fmaf(w[q].w, x.w, s);
            }
            out[((size_t)b * TT + (t0 + t)) * RR + r] = s;   // coalesced
        }
    }
}

// ---------------- Main recurrence -----------------------------------------
__global__ __launch_bounds__(THREADS, 1)
void reservoir_df(const float* __restrict__ W_hh,
                  const float* __restrict__ bias,
                  float* __restrict__ out,
                  u32* __restrict__ hbuf)
{
    const int tid  = threadIdx.x;
    const int bid  = blockIdx.x;
    const int g    = bid & 7;              // batch / group (same-XCD under round-robin)
    const int rank = bid >> 3;             // 0..31 within group
    const int lr   = tid >> 3;             // local row 0..31
    const int j    = tid & 7;              // k-slice within row
    const int row  = rank * 32 + lr;

    // W_hh slice: k in [j*128, j*128+128)
    float4 w4[KV4];
    {
        const float4* whh4 = (const float4*)(W_hh + (size_t)row * RR);
        #pragma unroll
        for (int i = 0; i < KV4; i++) w4[i] = whh4[j * KV4 + i];
    }
    const float brow = bias[row];

    __shared__ float hlds[2][1056];        // padded h tile per parity

    float* outg = out + (size_t)g * TT * RR;

    // drive prefetch (publishers only): dreg = drive[t][row], one step ahead
    float dreg = (j == 0) ? outg[row] : 0.0f;

    for (int t = 0; t < TT; t++) {
        const int par = t & 1;

        // ---- B: poll+load h_t: one sc0 dwordx4 = 4 tagged fp32.
        // Tag bit for step t is (t>>1)&1 (slot t&1 alternates occupants).
        const u32x4* sp4 = (const u32x4*)(hbuf + (size_t)par * SLOT_U32 + (size_t)g * RR) + tid;
        const u32x4 hv = poll4(sp4, (u32)((t >> 1) & 1));
        const float f0 = __uint_as_float(hv[0]);
        const float f1 = __uint_as_float(hv[1]);
        const float f2 = __uint_as_float(hv[2]);
        const float f3 = __uint_as_float(hv[3]);

        // ---- A: issue next-step drive prefetch (a full step of slack;
        // issued AFTER the poll so it never couples into the spin's vmcnt)
        float dnext = 0.0f;
        if (j == 0 && t + 1 < TT) dnext = outg[(size_t)(t + 1) * RR + row];

        // ---- C: coalesced out row t-1 (h_t == out[t-1]); block `rank` owns 32 cols
        if (t > 0 && lr == rank) {
            *(float4*)(outg + (size_t)(t - 1) * RR + 4 * tid) = make_float4(f0, f1, f2, f3);
        }

        // ---- D: stage into padded LDS
        *(float4*)&hlds[par][PAD(4 * tid)] = make_float4(f0, f1, f2, f3);

        __syncthreads();

        // ---- G: compute (bank-conflict-free j-sliced float4 reads)
        float4 acc = make_float4(0.f, 0.f, 0.f, 0.f);
        const float* hb = &hlds[par][j * 132];
        #pragma unroll
        for (int i = 0; i < KV4; i++) {
            float4 hvv = *(const float4*)(hb + 4 * i);
            acc.x = fmaf(w4[i].x, hvv.x, acc.x);
            acc.y = fmaf(w4[i].y, hvv.y, acc.y);
            acc.z = fmaf(w4[i].z, hvv.z, acc.z);
            acc.w = fmaf(w4[i].w, hvv.w, acc.w);
        }

        float s = (acc.x + acc.y) + (acc.z + acc.w);
        s += __shfl_xor(s, 1, 64);
        s += __shfl_xor(s, 2, 64);
        s += __shfl_xor(s, 4, 64);

        // ---- H: publish h_{t+1}: one relaxed agent (sc1, write-through) u32
        if (j == 0) {
            const float hold = hlds[par][PAD(row)];
            const float pre  = (1.0f - ALPHA) * hold + ALPHA * (s + dreg + brow);
            const float hnew = fast_tanh(pre);
            const u32 bits = (__float_as_uint(hnew) & ~1u) | (u32)(((t + 1) >> 1) & 1);
            st_rlx32(hbuf + (size_t)((t + 1) & 1) * SLOT_U32 + (size_t)g * RR + row, bits);
            dreg = dnext;
        }
    }

    // ---- final out row TT-1 from h_TT (slot 0, tag bit (4096>>1)&1 == 0)
    if (lr == rank) {
        const u32x4* sp4 = (const u32x4*)(hbuf + (size_t)g * RR) + tid;
        const u32x4 hv = poll4(sp4, 0u);
        *(float4*)(outg + (size_t)(TT - 1) * RR + 4 * tid) =
            make_float4(__uint_as_float(hv[0]), __uint_as_float(hv[1]),
                        __uint_as_float(hv[2]), __uint_as_float(hv[3]));
    }
}

extern "C" void kernel_launch(void* const* d_in, const int* in_sizes, int n_in,
                              void* d_out, int out_size, void* d_ws, size_t ws_size,
                              hipStream_t stream) {
    const float* feedback = (const float*)d_in[0];
    const float* driving  = (const float*)d_in[1];
    const float* W_fb     = (const float*)d_in[2];
    const float* W_in     = (const float*)d_in[3];
    const float* W_hh     = (const float*)d_in[4];
    const float* bias     = (const float*)d_in[5];
    float* out = (float*)d_out;

    u32* hbuf = (u32*)d_ws;
    // Slot 0 = 0x00: tag bit 0 + h = 0.0f == h_0, readable immediately at t=0.
    // Slot 1 = 0x01 per byte: tag bit 1 != expected tag 0 at t=1 -> readers
    // spin until the real h_1 stores land.
    hipMemsetAsync(d_ws, 0x00, SLOT_U32 * sizeof(u32), stream);
    hipMemsetAsync((char*)d_ws + SLOT_U32 * sizeof(u32), 0x01, SLOT_U32 * sizeof(u32), stream);

    // Prologue: materialize drive = fb@W_fb^T + dr@W_in^T into `out`
    // (consumed in-place by the recurrence, row t read at step t, row t
    // overwritten with h at step t+1). Same-stream kernels serialize.
    hipLaunchKernelGGL(drive_pre, dim3(GROUPS * (TT / TCH)), dim3(256), 0, stream,
                       feedback, driving, W_fb, W_in, out);

    void* args[] = { (void*)&W_hh, (void*)&bias, (void*)&out, (void*)&hbuf };
    hipError_t ce = hipLaunchCooperativeKernel((const void*)reservoir_df,
                                               dim3(GROUPS * BPG), dim3(THREADS), args, 0, stream);
    if (ce != hipSuccess) {
        // Cooperative launch failure fallback: the kernel uses no grid-wide
        // sync, only intra-group dataflow; at ~160 VGPR / 8.3 KB LDS all 256
        // blocks co-reside under a plain launch too.
        hipLaunchKernelGGL(reservoir_df, dim3(GROUPS * BPG), dim3(THREADS), 0, stream,
                           W_hh, bias, out, hbuf);
    }
}

// Round 2
// 10661.582 us; speedup vs baseline: 1.2759x; 1.2759x over previous
//
#include <hip/hip_runtime.h>
#include <math.h>

// ReservoirLayer: B=8, T=4096, R=1024, F=64, I=32
#define TT 4096
#define RR 1024
#define FF 64
#define II 32
#define GROUPS 8                 // one group per batch element
#define BPG 32                   // blocks per group
#define THREADS 256
#define KV4 32                   // float4 of W_hh per thread
#define ALPHA 0.9f
#define TCH 32                   // timesteps per prologue block

typedef unsigned long long u64;
typedef unsigned int u32;
typedef u32 u32x4 __attribute__((ext_vector_type(4)));

#define SLOT_U32 (GROUPS * RR)           // 8192 u32 per parity slot (32 KB)
#define PAD(i) ((i) + (((i) >> 7) << 2)) // +4 floats per 128-float chunk

// Agent-scope 16B poll load: sc1 reads the device coherence point (MALL),
// always coherent with the atomic-swap publishes (no stale-L2 hazard, no
// fallback path needed). One request per 16B — round 0 used 2x u64 = 2
// requests per thread, so this halves poll request count into the MALL.
__device__ __forceinline__ u32x4 ld_agent16(const u32x4* p) {
    u32x4 v;
    asm volatile("global_load_dwordx4 %0, %1, off sc1\n\t"
                 "s_waitcnt vmcnt(0)"
                 : "=v"(v) : "v"(p) : "memory");
    return v;
}

__device__ __forceinline__ u32x4 poll4(const u32x4* p, u32 wtag) {
    u32x4 v = ld_agent16(p);
    while ((((v[0] ^ wtag) | (v[1] ^ wtag) | (v[2] ^ wtag) | (v[3] ^ wtag)) & 1u) != 0u)
        v = ld_agent16(p);
    return v;
}

// Publish via atomic swap (relaxed, agent scope, result unused -> compiler
// emits global_atomic_swap without sc0, fire-and-forget). Rationale: a plain
// relaxed sc1 STORE of 32B-of-a-64B-line per wave can sit in per-CU
// write-combine/store buffering before draining to the MALL; an atomic is
// executed AT the coherence point and cannot linger. Round 0/1 only ever
// changed the read side — this is the first probe of publish visibility.
__device__ __forceinline__ void st_pub(u32* p, u32 v) {
    (void)__hip_atomic_exchange(p, v, __ATOMIC_RELAXED, __HIP_MEMORY_SCOPE_AGENT);
}

// tanh via v_exp_f32: (e^{2|x|}-1)/(e^{2|x|}+1), |x| clamped at 10
// (tanh(10)=1-8e-9 == 1.0f). Error ~2^-21/step, far below the already
// tolerated tag-LSB clobber.
__device__ __forceinline__ float fast_tanh(float x) {
    float ax = fabsf(x);
    float e  = __expf(2.0f * fminf(ax, 10.0f));
    float r  = (e - 1.0f) * __builtin_amdgcn_rcpf(e + 1.0f);
    return x < 0.0f ? -r : r;
}

// ---------------- Prologue: drive[b,t,r] = fb·W_fb^T + dr·W_in^T -> out ----
// out row t is consumed (as drive) at step t of the recurrence and only
// overwritten (with h_t) at step t+1 — safe in-place dataflow. Bias is
// added in the main kernel (brow).
__global__ __launch_bounds__(256, 1)
void drive_pre(const float* __restrict__ feedback,
               const float* __restrict__ driving,
               const float* __restrict__ W_fb,
               const float* __restrict__ W_in,
               float* __restrict__ out)
{
    const int tid = threadIdx.x;
    const int b   = blockIdx.x >> 7;            // 128 chunks per batch
    const int t0  = (blockIdx.x & 127) * TCH;

    __shared__ float xch[TCH][96];              // [t][ fb(64) | dr(32) ]

    const float4* fb4 = (const float4*)(feedback + ((size_t)b * TT + t0) * FF);
    #pragma unroll
    for (int q = 0; q < 2; q++) {
        int i = tid + 256 * q;                  // 0..511 : 32t x 16 float4
        float4 v = fb4[i];
        *(float4*)&xch[i >> 4][(i & 15) << 2] = v;
    }
    {
        const float4* dr4 = (const float4*)(driving + ((size_t)b * TT + t0) * II);
        float4 v = dr4[tid];                    // 0..255 : 32t x 8 float4
        *(float4*)&xch[tid >> 3][64 + ((tid & 7) << 2)] = v;
    }
    __syncthreads();

    #pragma unroll 1
    for (int p = 0; p < 4; p++) {
        const int r = p * 256 + tid;
        float4 w[24];
        const float4* wf4 = (const float4*)(W_fb + (size_t)r * FF);
        #pragma unroll
        for (int q = 0; q < 16; q++) w[q] = wf4[q];
        const float4* wi4 = (const float4*)(W_in + (size_t)r * II);
        #pragma unroll
        for (int q = 0; q < 8; q++) w[16 + q] = wi4[q];

        for (int t = 0; t < TCH; t++) {
            float s = 0.0f;
            #pragma unroll
            for (int q = 0; q < 24; q++) {
                float4 x = *(const float4*)&xch[t][q << 2]; // broadcast read
                s = fmaf(w[q].x, x.x, s);
                s = fmaf(w[q].y, x.y, s);
                s = fmaf(w[q].z, x.z, s);
                s = fmaf(w[q].w, x.w, s);
            }
            out[((size_t)b * TT + (t0 + t)) * RR + r] = s;   // coalesced
        }
    }
}

// ---------------- Main recurrence -----------------------------------------
__global__ __launch_bounds__(THREADS, 1)
void reservoir_df(const float* __restrict__ W_hh,
                  const float* __restrict__ bias,
                  float* __restrict__ out,
                  u32* __restrict__ hbuf)
{
    const int tid  = threadIdx.x;
    const int bid  = blockIdx.x;
    const int g    = bid & 7;              // batch / group
    const int rank = bid >> 3;             // 0..31 within group
    const int lr   = tid >> 3;             // local row 0..31
    const int j    = tid & 7;              // k-slice within row
    const int row  = rank * 32 + lr;

    // W_hh slice: k in [j*128, j*128+128)
    float4 w4[KV4];
    {
        const float4* whh4 = (const float4*)(W_hh + (size_t)row * RR);
        #pragma unroll
        for (int i = 0; i < KV4; i++) w4[i] = whh4[j * KV4 + i];
    }
    const float brow = bias[row];

    __shared__ float hlds[2][1056];        // padded h tile per parity

    float* outg = out + (size_t)g * TT * RR;

    // drive prefetch (publishers only): dreg = drive[t][row], one step ahead
    float dreg = (j == 0) ? outg[row] : 0.0f;

    for (int t = 0; t < TT; t++) {
        const int par = t & 1;

        // ---- B: poll+load h_t: one sc1 dwordx4 = 4 tagged fp32.
        // Tag bit for step t is (t>>1)&1 (slot t&1 alternates occupants).
        const u32x4* sp4 = (const u32x4*)(hbuf + (size_t)par * SLOT_U32 + (size_t)g * RR) + tid;
        const u32x4 hv = poll4(sp4, (u32)((t >> 1) & 1));
        const float f0 = __uint_as_float(hv[0]);
        const float f1 = __uint_as_float(hv[1]);
        const float f2 = __uint_as_float(hv[2]);
        const float f3 = __uint_as_float(hv[3]);

        // ---- A: issue next-step drive prefetch (a full step of slack;
        // issued AFTER the poll so it never couples into the spin's vmcnt)
        float dnext = 0.0f;
        if (j == 0 && t + 1 < TT) dnext = outg[(size_t)(t + 1) * RR + row];

        // ---- C: coalesced out row t-1 (h_t == out[t-1]); block `rank` owns 32 cols
        if (t > 0 && lr == rank) {
            *(float4*)(outg + (size_t)(t - 1) * RR + 4 * tid) = make_float4(f0, f1, f2, f3);
        }

        // ---- D: stage into padded LDS
        *(float4*)&hlds[par][PAD(4 * tid)] = make_float4(f0, f1, f2, f3);

        __syncthreads();

        // ---- G: compute (bank-conflict-free j-sliced float4 reads)
        float4 acc = make_float4(0.f, 0.f, 0.f, 0.f);
        const float* hb = &hlds[par][j * 132];
        #pragma unroll
        for (int i = 0; i < KV4; i++) {
            float4 hvv = *(const float4*)(hb + 4 * i);
            acc.x = fmaf(w4[i].x, hvv.x, acc.x);
            acc.y = fmaf(w4[i].y, hvv.y, acc.y);
            acc.z = fmaf(w4[i].z, hvv.z, acc.z);
            acc.w = fmaf(w4[i].w, hvv.w, acc.w);
        }

        float s = (acc.x + acc.y) + (acc.z + acc.w);
        s += __shfl_xor(s, 1, 64);
        s += __shfl_xor(s, 2, 64);
        s += __shfl_xor(s, 4, 64);

        // ---- H: publish h_{t+1}: one relaxed agent atomic-swap u32
        if (j == 0) {
            const float hold = hlds[par][PAD(row)];
            const float pre  = (1.0f - ALPHA) * hold + ALPHA * (s + dreg + brow);
            const float hnew = fast_tanh(pre);
            const u32 bits = (__float_as_uint(hnew) & ~1u) | (u32)(((t + 1) >> 1) & 1);
            st_pub(hbuf + (size_t)((t + 1) & 1) * SLOT_U32 + (size_t)g * RR + row, bits);
            dreg = dnext;
        }
    }

    // ---- final out row TT-1 from h_TT (slot 0, tag bit (4096>>1)&1 == 0)
    if (lr == rank) {
        const u32x4* sp4 = (const u32x4*)(hbuf + (size_t)g * RR) + tid;
        const u32x4 hv = poll4(sp4, 0u);
        *(float4*)(outg + (size_t)(TT - 1) * RR + 4 * tid) =
            make_float4(__uint_as_float(hv[0]), __uint_as_float(hv[1]),
                        __uint_as_float(hv[2]), __uint_as_float(hv[3]));
    }
}

extern "C" void kernel_launch(void* const* d_in, const int* in_sizes, int n_in,
                              void* d_out, int out_size, void* d_ws, size_t ws_size,
                              hipStream_t stream) {
    const float* feedback = (const float*)d_in[0];
    const float* driving  = (const float*)d_in[1];
    const float* W_fb     = (const float*)d_in[2];
    const float* W_in     = (const float*)d_in[3];
    const float* W_hh     = (const float*)d_in[4];
    const float* bias     = (const float*)d_in[5];
    float* out = (float*)d_out;

    u32* hbuf = (u32*)d_ws;
    // Slot 0 = 0x00: tag bit 0 + h = 0.0f == h_0, readable immediately at t=0.
    // Slot 1 = 0x01 per byte: tag bit 1 != expected tag 0 at t=1 -> readers
    // spin until the real h_1 stores land.
    hipMemsetAsync(d_ws, 0x00, SLOT_U32 * sizeof(u32), stream);
    hipMemsetAsync((char*)d_ws + SLOT_U32 * sizeof(u32), 0x01, SLOT_U32 * sizeof(u32), stream);

    // Prologue: materialize drive = fb@W_fb^T + dr@W_in^T into `out`
    // (consumed in-place by the recurrence, row t read at step t, row t
    // overwritten with h at step t+1). Same-stream kernels serialize.
    hipLaunchKernelGGL(drive_pre, dim3(GROUPS * (TT / TCH)), dim3(256), 0, stream,
                       feedback, driving, W_fb, W_in, out);

    void* args[] = { (void*)&W_hh, (void*)&bias, (void*)&out, (void*)&hbuf };
    hipError_t ce = hipLaunchCooperativeKernel((const void*)reservoir_df,
                                               dim3(GROUPS * BPG), dim3(THREADS), args, 0, stream);
    if (ce != hipSuccess) {
        // Cooperative launch failure fallback: the kernel uses no grid-wide
        // sync, only intra-group dataflow; at ~90 VGPR / 8.5 KB LDS all 256
        // blocks co-reside under a plain launch too.
        hipLaunchKernelGGL(reservoir_df, dim3(GROUPS * BPG), dim3(THREADS), 0, stream,
                           W_hh, bias, out, hbuf);
    }
}

// Round 3
// 8565.292 us; speedup vs baseline: 1.5881x; 1.2447x over previous
//
#include <hip/hip_runtime.h>
#include <math.h>

// ReservoirLayer: B=8, T=4096, R=1024, F=64, I=32
#define TT 4096
#define RR 1024
#define FF 64
#define II 32
#define GROUPS 8                 // one group per batch element
#define BPG 32                   // blocks per group
#define THREADS 256
#define KV4 32                   // float4 of W_hh per thread
#define ALPHA 0.9f
#define TCH 32                   // timesteps per prologue block

typedef unsigned long long u64;
typedef unsigned int u32;
typedef u32 u32x4 __attribute__((ext_vector_type(4)));

#define SLOT_U32 (GROUPS * RR)           // 8192 u32 per parity slot (32 KB)
#define CNT_BASE (2 * SLOT_U32)          // u32 index of epoch-counter area
#define PAD(i) ((i) + (((i) >> 7) << 2)) // +4 floats per 128-float chunk

// Agent-scope (sc1, MALL-coherent) loads.
__device__ __forceinline__ u32x4 ld_agent16(const u32x4* p) {
    u32x4 v;
    asm volatile("global_load_dwordx4 %0, %1, off sc1\n\t"
                 "s_waitcnt vmcnt(0)"
                 : "=v"(v) : "v"(p) : "memory");
    return v;
}
__device__ __forceinline__ u32 ld_agent32(const u32* p) {
    u32 v;
    asm volatile("global_load_dword %0, %1, off sc1\n\t"
                 "s_waitcnt vmcnt(0)"
                 : "=v"(v) : "v"(p) : "memory");
    return v;
}

// Tag-verified read. With the epoch counter, the first load is almost always
// fresh; the spin path only covers add-vs-swap in-flight reorder (rare).
__device__ __forceinline__ u32x4 poll4(const u32x4* p, u32 wtag) {
    u32x4 v = ld_agent16(p);
    while ((((v[0] ^ wtag) | (v[1] ^ wtag) | (v[2] ^ wtag) | (v[3] ^ wtag)) & 1u) != 0u)
        v = ld_agent16(p);
    return v;
}

// Publish via atomic swap (relaxed, agent, result unused): executed AT the
// MALL, cannot linger in per-CU write buffering (proved faster than plain
// sc1 stores in rounds 0->2). 64-bit variant packs two rows -> halves the
// atomic count (8192 -> 4096 per step).
__device__ __forceinline__ void st_pub64(u64* p, u64 v) {
    (void)__hip_atomic_exchange(p, v, __ATOMIC_RELAXED, __HIP_MEMORY_SCOPE_AGENT);
}
__device__ __forceinline__ void cnt_add(u32* p, u32 v) {
    (void)__hip_atomic_fetch_add(p, v, __ATOMIC_RELAXED, __HIP_MEMORY_SCOPE_AGENT);
}

// tanh via v_exp_f32: (e^{2|x|}-1)/(e^{2|x|}+1), |x| clamped at 10.
__device__ __forceinline__ float fast_tanh(float x) {
    float ax = fabsf(x);
    float e  = __expf(2.0f * fminf(ax, 10.0f));
    float r  = (e - 1.0f) * __builtin_amdgcn_rcpf(e + 1.0f);
    return x < 0.0f ? -r : r;
}

// ---------------- Prologue: drive[b,t,r] = fb·W_fb^T + dr·W_in^T -> out ----
// out row t is consumed (as drive) at step t and only overwritten (with h)
// at step t+1 — safe in-place dataflow. Bias added in the main kernel.
__global__ __launch_bounds__(256, 1)
void drive_pre(const float* __restrict__ feedback,
               const float* __restrict__ driving,
               const float* __restrict__ W_fb,
               const float* __restrict__ W_in,
               float* __restrict__ out)
{
    const int tid = threadIdx.x;
    const int b   = blockIdx.x >> 7;            // 128 chunks per batch
    const int t0  = (blockIdx.x & 127) * TCH;

    __shared__ float xch[TCH][96];              // [t][ fb(64) | dr(32) ]

    const float4* fb4 = (const float4*)(feedback + ((size_t)b * TT + t0) * FF);
    #pragma unroll
    for (int q = 0; q < 2; q++) {
        int i = tid + 256 * q;                  // 0..511 : 32t x 16 float4
        float4 v = fb4[i];
        *(float4*)&xch[i >> 4][(i & 15) << 2] = v;
    }
    {
        const float4* dr4 = (const float4*)(driving + ((size_t)b * TT + t0) * II);
        float4 v = dr4[tid];                    // 0..255 : 32t x 8 float4
        *(float4*)&xch[tid >> 3][64 + ((tid & 7) << 2)] = v;
    }
    __syncthreads();

    #pragma unroll 1
    for (int p = 0; p < 4; p++) {
        const int r = p * 256 + tid;
        float4 w[24];
        const float4* wf4 = (const float4*)(W_fb + (size_t)r * FF);
        #pragma unroll
        for (int q = 0; q < 16; q++) w[q] = wf4[q];
        const float4* wi4 = (const float4*)(W_in + (size_t)r * II);
        #pragma unroll
        for (int q = 0; q < 8; q++) w[16 + q] = wi4[q];

        for (int t = 0; t < TCH; t++) {
            float s = 0.0f;
            #pragma unroll
            for (int q = 0; q < 24; q++) {
                float4 x = *(const float4*)&xch[t][q << 2]; // broadcast read
                s = fmaf(w[q].x, x.x, s);
                s = fmaf(w[q].y, x.y, s);
                s = fmaf(w[q].z, x.z, s);
                s = fmaf(w[q].w, x.w, s);
            }
            out[((size_t)b * TT + (t0 + t)) * RR + r] = s;   // coalesced
        }
    }
}

// ---------------- Main recurrence -----------------------------------------
// Handshake per step:
//   publishers: 16x atomic_swap_x2 per block (h rows, LSB-tagged)
//   B3 barrier -> next iter: tid0 atomic_add(+32) to cnt[g][par]
//   readers: tid0 polls cnt until 1024*ceil(t/2)  (256 pollers device-wide)
//   then ALL threads one-shot ld_agent16 + tag verify.
// Safety: tags make counter over-attestation (in-flight reorder) harmless;
// parity-2 reuse is safe by induction (P publishes h_{t+2} only after all
// blocks published h_{t+1}, which requires them to have fully read h_t).
__global__ __launch_bounds__(THREADS, 1)
void reservoir_df(const float* __restrict__ W_hh,
                  const float* __restrict__ bias,
                  float* __restrict__ out,
                  u32* __restrict__ hbuf)
{
    const int tid  = threadIdx.x;
    const int bid  = blockIdx.x;
    const int g    = bid & 7;              // batch / group
    const int rank = bid >> 3;             // 0..31 within group
    const int lr   = tid >> 3;             // local row 0..31
    const int j    = tid & 7;              // k-slice within row
    const int row  = rank * 32 + lr;

    // W_hh slice: k in [j*128, j*128+128)
    float4 w4[KV4];
    {
        const float4* whh4 = (const float4*)(W_hh + (size_t)row * RR);
        #pragma unroll
        for (int i = 0; i < KV4; i++) w4[i] = whh4[j * KV4 + i];
    }
    const float brow = bias[row];

    __shared__ float hlds[2][1056];        // padded h tile per parity

    float* outg = out + (size_t)g * TT * RR;
    u32* cnt[2] = { hbuf + CNT_BASE + (g * 2 + 0) * 16,    // own 64B line each
                    hbuf + CNT_BASE + (g * 2 + 1) * 16 };

    // drive prefetch (publishers only): dreg = drive[t][row], one step ahead
    float dreg = (j == 0) ? outg[row] : 0.0f;

    for (int t = 0; t < TT; t++) {
        const int par = t & 1;

        // ---- E: attest previous publishes + detect epoch (single poller) --
        if (tid == 0) {
            u32* cp = cnt[par];
            if (t > 0) cnt_add(cp, 32u);               // this block's h_t rows
            const u32 target = (u32)((t + 1) >> 1) << 10;  // 1024*ceil(t/2)
            if (target) while (ld_agent32(cp) < target) {}
        }

        // ---- A: next-step drive prefetch; latency hides under the detect
        // phase (poll4's vmcnt(0) will also drain it, after the barrier).
        float dnext = 0.0f;
        if (j == 0 && t + 1 < TT) dnext = outg[(size_t)(t + 1) * RR + row];

        __syncthreads();                                // B1: epoch visible

        // ---- B: one-shot read of h_t (tag-verified; ~always fresh) --------
        const u32x4* sp4 = (const u32x4*)(hbuf + (size_t)par * SLOT_U32 + (size_t)g * RR) + tid;
        const u32x4 hv = poll4(sp4, (u32)((t >> 1) & 1));
        const float f0 = __uint_as_float(hv[0]);
        const float f1 = __uint_as_float(hv[1]);
        const float f2 = __uint_as_float(hv[2]);
        const float f3 = __uint_as_float(hv[3]);

        // ---- C: coalesced out row t-1 (h_t == out[t-1]); block `rank` owns 32 cols
        if (t > 0 && lr == rank) {
            *(float4*)(outg + (size_t)(t - 1) * RR + 4 * tid) = make_float4(f0, f1, f2, f3);
        }

        // ---- D: stage into padded LDS
        *(float4*)&hlds[par][PAD(4 * tid)] = make_float4(f0, f1, f2, f3);

        __syncthreads();                                // B2

        // ---- G: compute (bank-conflict-free j-sliced float4 reads)
        float4 acc = make_float4(0.f, 0.f, 0.f, 0.f);
        const float* hb = &hlds[par][j * 132];
        #pragma unroll
        for (int i = 0; i < KV4; i++) {
            float4 hvv = *(const float4*)(hb + 4 * i);
            acc.x = fmaf(w4[i].x, hvv.x, acc.x);
            acc.y = fmaf(w4[i].y, hvv.y, acc.y);
            acc.z = fmaf(w4[i].z, hvv.z, acc.z);
            acc.w = fmaf(w4[i].w, hvv.w, acc.w);
        }

        float s = (acc.x + acc.y) + (acc.z + acc.w);
        s += __shfl_xor(s, 1, 64);
        s += __shfl_xor(s, 2, 64);
        s += __shfl_xor(s, 4, 64);

        // ---- H: publish h_{t+1}, packed 2 rows per 64-bit atomic swap -----
        u32 bits = 0u;
        if (j == 0) {
            const float hold = hlds[par][PAD(row)];
            const float pre  = (1.0f - ALPHA) * hold + ALPHA * (s + dreg + brow);
            const float hnew = fast_tanh(pre);
            bits = (__float_as_uint(hnew) & ~1u) | (u32)(((t + 1) >> 1) & 1);
            dreg = dnext;
        }
        const u32 partner = __shfl_xor(bits, 8, 64);    // row+1's bits -> even-row lane
        if ((tid & 15) == 0) {                          // rows even: 8B-aligned
            u64* dst = (u64*)(hbuf + (size_t)((t + 1) & 1) * SLOT_U32 + (size_t)g * RR + row);
            st_pub64(dst, (u64)bits | ((u64)partner << 32));
        }

        __syncthreads();   // B3: all waves' swaps issued before next iter's add
    }

    // ---- final out row TT-1 from h_TT (slot 0, tag (4096>>1)&1 == 0);
    // pure tag-poll (no counter add was made for h_TT — nobody else reads it)
    if (lr == rank) {
        const u32x4* sp4 = (const u32x4*)(hbuf + (size_t)g * RR) + tid;
        const u32x4 hv = poll4(sp4, 0u);
        *(float4*)(outg + (size_t)(TT - 1) * RR + 4 * tid) =
            make_float4(__uint_as_float(hv[0]), __uint_as_float(hv[1]),
                        __uint_as_float(hv[2]), __uint_as_float(hv[3]));
    }
}

extern "C" void kernel_launch(void* const* d_in, const int* in_sizes, int n_in,
                              void* d_out, int out_size, void* d_ws, size_t ws_size,
                              hipStream_t stream) {
    const float* feedback = (const float*)d_in[0];
    const float* driving  = (const float*)d_in[1];
    const float* W_fb     = (const float*)d_in[2];
    const float* W_in     = (const float*)d_in[3];
    const float* W_hh     = (const float*)d_in[4];
    const float* bias     = (const float*)d_in[5];
    float* out = (float*)d_out;

    u32* hbuf = (u32*)d_ws;
    // ws layout: slot0 (32KB) | slot1 (32KB) | 16x 64B epoch counters (1KB)
    // = 66,560 B total (round 1 proved >= 66,560 B available).
    // Slot 0 = 0x00: tag 0 + h = 0.0f == h_0, readable at t=0 (target 0).
    // Slot 1 = 0x01: tag 1 != expected 0 at t=1 -> tag spin until real h_1.
    hipMemsetAsync(d_ws, 0x00, SLOT_U32 * sizeof(u32), stream);
    hipMemsetAsync((char*)d_ws + SLOT_U32 * sizeof(u32), 0x01, SLOT_U32 * sizeof(u32), stream);
    hipMemsetAsync((char*)d_ws + 2 * SLOT_U32 * sizeof(u32), 0x00, 16 * 64, stream);

    // Prologue: materialize drive = fb@W_fb^T + dr@W_in^T into `out`
    // (consumed in-place; same-stream kernels serialize).
    hipLaunchKernelGGL(drive_pre, dim3(GROUPS * (TT / TCH)), dim3(256), 0, stream,
                       feedback, driving, W_fb, W_in, out);

    void* args[] = { (void*)&W_hh, (void*)&bias, (void*)&out, (void*)&hbuf };
    hipError_t ce = hipLaunchCooperativeKernel((const void*)reservoir_df,
                                               dim3(GROUPS * BPG), dim3(THREADS), args, 0, stream);
    if (ce != hipSuccess) {
        // Fallback: no grid-wide sync used, only intra-group dataflow; at
        // ~90 VGPR / 8.5 KB LDS all 256 blocks co-reside under plain launch.
        hipLaunchKernelGGL(reservoir_df, dim3(GROUPS * BPG), dim3(THREADS), 0, stream,
                           W_hh, bias, out, hbuf);
    }
}